// Round 12
// baseline (805.080 us; speedup 1.0000x reference)
//
#include <hip/hip_runtime.h>
#include <math.h>

#define NXG 512
#define NPTS (NXG * NXG)
#define NB 4
#define NT 256
#define NM 256
#define K 16                // steps per chunk
#define NCH (NT / K)        // 16 chunks
#define WROWS 128           // window rows (64 interior + 2*32 halo)
#define WCOLS 128           // window cols
#define NTHR 1024           // 16 row-groups x 64 col-threads; 8x2 cells each
#define NTILES 64           // 8x8 tiles (64x64 interior) cover 512x512
#define LROWS 72            // LDS slots: (16+2 pad) groups x 4 rows

// ---------------------------------------------------------------------------
__global__ __launch_bounds__(256) void zero_kernel(float4* __restrict__ p) {
    p[blockIdx.x * 256 + threadIdx.x] = make_float4(0.f, 0.f, 0.f, 0.f);
}

// DPP wave shifts. One wave == one 8-row x 128-col band (64 col-threads),
// so lane+-1 IS the col neighbor; junk enters only at lanes 0/63 =
// window-edge cols 0,1 / 126,127 — garbage-tolerant (32-wide halo).
__device__ __forceinline__ float dpp_left(float v) {   // from lane-1
    return __int_as_float(__builtin_amdgcn_mov_dpp(__float_as_int(v),
                                                   0x138, 0xf, 0xf, true));
}
__device__ __forceinline__ float dpp_right(float v) {  // from lane+1
    return __int_as_float(__builtin_amdgcn_mov_dpp(__float_as_int(v),
                                                   0x130, 0xf, 0xf, true));
}

// ---------------------------------------------------------------------------
// One row of 2 cells -> pn; consumed immediately by caller (no spill).
// ---------------------------------------------------------------------------
__device__ __forceinline__ void row_calc(
    const float (&cur)[8][2], const float (&prv)[8][2],
    const float (&v2R)[8][2], int r,
    const float* __restrict__ xm2, const float* __restrict__ xm1,
    const float* __restrict__ xp1, const float* __restrict__ xp2,
    int injCell, float add, float (&pn)[2])
{
    float ym2 = dpp_left(cur[r][0]);   // col c0-2
    float ym1 = dpp_left(cur[r][1]);   // col c0-1
    float yp2 = dpp_right(cur[r][0]);  // col c0+2
    float yp3 = dpp_right(cur[r][1]);  // col c0+3
    {
        float cc = cur[r][0];
        float sum1 = (xm1[0] + xp1[0]) + (ym1 + cur[r][1]);
        float sum2 = (xm2[0] + xp2[0]) + (ym2 + yp2);
        float w = fmaf(-60.0f, cc, fmaf(16.0f, sum1, -sum2));
        float p = fmaf(v2R[r][0], w, fmaf(2.0f, cc, -prv[r][0]));
        if (((r << 1) | 0) == injCell) p += add;
        pn[0] = p;
    }
    {
        float cc = cur[r][1];
        float sum1 = (xm1[1] + xp1[1]) + (cur[r][0] + yp2);
        float sum2 = (xm2[1] + xp2[1]) + (ym1 + yp3);
        float w = fmaf(-60.0f, cc, fmaf(16.0f, sum1, -sum2));
        float p = fmaf(v2R[r][1], w, fmaf(2.0f, cc, -prv[r][1]));
        if (((r << 1) | 1) == injCell) p += add;
        pn[1] = p;
    }
}

// ---------------------------------------------------------------------------
// One step: 8x2 cells in registers; x-halo rows -2,-1,+8,+9 from LDS (b64);
// y-halo via DPP. Halo-free rows 2..5 first; results consumed per-row.
// ---------------------------------------------------------------------------
__device__ __forceinline__ void do_step(
    const float* __restrict__ Lc, float* __restrict__ Ln,
    float* __restrict__ out,
    const float (&v2R)[8][2], float (&cur)[8][2], float (&prv)[8][2],
    int base, int c0, int injCell, float add,
    int m1Cell, int m1Addr, int m2Cell, int m2Addr, int n)
{
    float2 a2 = *(const float2*)&Lc[(base - 2) * WCOLS + c0];  // row r0-2
    float2 b2 = *(const float2*)&Lc[(base - 1) * WCOLS + c0];  // row r0-1
    float2 c2 = *(const float2*)&Lc[(base + 4) * WCOLS + c0];  // row r0+8
    float2 d2 = *(const float2*)&Lc[(base + 5) * WCOLS + c0];  // row r0+9

    float pn[2];
#pragma unroll
    for (int r = 2; r < 6; ++r) {
        row_calc(cur, prv, v2R, r, cur[r - 2], cur[r - 1], cur[r + 1],
                 cur[r + 2], injCell, add, pn);
        if (m1Cell >= 0 && (m1Cell >> 1) == r) out[m1Addr | n] = pn[m1Cell & 1];
        if (m2Cell >= 0 && (m2Cell >> 1) == r) out[m2Addr | n] = pn[m2Cell & 1];
        prv[r][0] = pn[0]; prv[r][1] = pn[1];
    }

    float ha[2] = {a2.x, a2.y};
    float hb[2] = {b2.x, b2.y};
    row_calc(cur, prv, v2R, 0, ha, hb, cur[1], cur[2], injCell, add, pn);
    if (m1Cell >= 0 && (m1Cell >> 1) == 0) out[m1Addr | n] = pn[m1Cell & 1];
    if (m2Cell >= 0 && (m2Cell >> 1) == 0) out[m2Addr | n] = pn[m2Cell & 1];
    *(float2*)&Ln[(base + 0) * WCOLS + c0] = make_float2(pn[0], pn[1]);
    prv[0][0] = pn[0]; prv[0][1] = pn[1];

    row_calc(cur, prv, v2R, 1, hb, cur[0], cur[2], cur[3], injCell, add, pn);
    if (m1Cell >= 0 && (m1Cell >> 1) == 1) out[m1Addr | n] = pn[m1Cell & 1];
    if (m2Cell >= 0 && (m2Cell >> 1) == 1) out[m2Addr | n] = pn[m2Cell & 1];
    *(float2*)&Ln[(base + 1) * WCOLS + c0] = make_float2(pn[0], pn[1]);
    prv[1][0] = pn[0]; prv[1][1] = pn[1];

    float hc[2] = {c2.x, c2.y};
    float hd[2] = {d2.x, d2.y};
    row_calc(cur, prv, v2R, 6, cur[4], cur[5], cur[7], hc, injCell, add, pn);
    if (m1Cell >= 0 && (m1Cell >> 1) == 6) out[m1Addr | n] = pn[m1Cell & 1];
    if (m2Cell >= 0 && (m2Cell >> 1) == 6) out[m2Addr | n] = pn[m2Cell & 1];
    *(float2*)&Ln[(base + 2) * WCOLS + c0] = make_float2(pn[0], pn[1]);
    prv[6][0] = pn[0]; prv[6][1] = pn[1];

    row_calc(cur, prv, v2R, 7, cur[5], cur[6], hc, hd, injCell, add, pn);
    if (m1Cell >= 0 && (m1Cell >> 1) == 7) out[m1Addr | n] = pn[m1Cell & 1];
    if (m2Cell >= 0 && (m2Cell >> 1) == 7) out[m2Addr | n] = pn[m2Cell & 1];
    *(float2*)&Ln[(base + 3) * WCOLS + c0] = make_float2(pn[0], pn[1]);
    prv[7][0] = pn[0]; prv[7][1] = pn[1];
}

// ---------------------------------------------------------------------------
__global__ __launch_bounds__(NTHR, 4) void chunk_kernel(
    const float* __restrict__ x,       // (4,1,256,256)
    const float* __restrict__ se,      // (64,)
    float* __restrict__ out,           // (4,1,256,256) = [b][m][t]
    const float* __restrict__ gA,      // f_{n0}
    const float* __restrict__ gB,      // f_{n0-1}
    float* __restrict__ wA,            // f_{n0+K}
    float* __restrict__ wB,            // f_{n0+K-1}
    const int2* __restrict__ thrTab,   // NTILES x NTHR
    const float* __restrict__ srcT,
    int n0)
{
    __shared__ __align__(16) float L0[LROWS * WCOLS];
    __shared__ __align__(16) float L1[LROWS * WCOLS];

    const int tid = threadIdx.x;
    const int blk = blockIdx.x;
    const int b   = blk >> 6;          // batch
    const int tb  = blk & 63;          // tile
    const int gi0 = (tb >> 3) << 6;    // interior origin rows
    const int gj0 = (tb & 7) << 6;     // interior origin cols
    const int bi0 = gi0 - 32;
    const int bj0 = gj0 - 32;

    const int grp = tid >> 6;          // 0..15 (== wave id)
    const int r0  = grp << 3;          // own window rows r0..r0+7
    const int c0  = (tid & 63) << 1;   // own window cols (2)
    const int base = (grp + 1) << 2;   // LDS slot base

    // ---- prologue: own cells of f_{n0}, f_{n0-1}; v2/12 ----
    float curR[8][2], prvR[8][2], v2R[8][2];
    const float* gAb = gA + (b << 18);
    const float* gBb = gB + (b << 18);
#pragma unroll
    for (int r = 0; r < 8; ++r) {
        int gi = (bi0 + r0 + r) & 511;
        int gj = (bj0 + c0) & 511;
        float2 cv = *(const float2*)&gAb[(gi << 9) | gj];
        float2 pv = *(const float2*)&gBb[(gi << 9) | gj];
        curR[r][0] = cv.x; curR[r][1] = cv.y;
        prvR[r][0] = pv.x; prvR[r][1] = pv.y;
#pragma unroll
        for (int c = 0; c < 2; ++c) {
            int gjc = gj + c;
            float v;
            if (gi < 55 || gi >= 457 || gjc < 55 || gjc >= 457) v = 1e-6f;
            else if (gi >= 128 && gi < 384 && gjc >= 128 && gjc < 384)
                v = x[(b << 16) | ((gi - 128) << 8) | (gjc - 128)];
            else v = 1.5f;
            float a = (2e-05f * v) / 1e-04f;
            v2R[r][c] = a * a * (1.0f / 12.0f);
        }
    }

    // ---- inj/meas: one int2 (cell = (row<<1)|col, 0..15) ----
    const int2 tw = thrTab[(tb << 10) | tid];
    int injCell = -1;  float injV = 0.0f;
    if (tw.x >= 0) { injCell = tw.x & 15; injV = 0.09f * se[tw.x >> 8]; }
    int m1Cell = -1, m1Addr = 0, m2Cell = -1, m2Addr = 0;
    {
        int h1 = tw.y & 0xFFFF, h2 = (tw.y >> 16) & 0xFFFF;
        if (h1 & 0x8000) { m1Cell = (h1 >> 8) & 15; m1Addr = (b << 16) | ((h1 & 255) << 8); }
        if (h2 & 0x8000) { m2Cell = (h2 >> 8) & 15; m2Addr = (b << 16) | ((h2 & 255) << 8); }
    }

    // ---- publish f_{n0} boundary rows ----
    *(float2*)&L0[(base + 0) * WCOLS + c0] = make_float2(curR[0][0], curR[0][1]);
    *(float2*)&L0[(base + 1) * WCOLS + c0] = make_float2(curR[1][0], curR[1][1]);
    *(float2*)&L0[(base + 2) * WCOLS + c0] = make_float2(curR[6][0], curR[6][1]);
    *(float2*)&L0[(base + 3) * WCOLS + c0] = make_float2(curR[7][0], curR[7][1]);
    __syncthreads();

    const bool wbThread = (r0 >= 32 && r0 < 96 && c0 >= 32 && c0 < 96);

#pragma unroll 1
    for (int s = 0; s < K; s += 2) {
        int n = n0 + s;
        do_step(L0, L1, out, v2R, curR, prvR, base, c0,
                injCell, injV * srcT[n], m1Cell, m1Addr, m2Cell, m2Addr, n);
        if (s == K - 2 && wbThread) {     // prvR holds f_{n0+K-1}
            int gj = gj0 + (c0 - 32);
#pragma unroll
            for (int r = 0; r < 8; ++r) {
                int gi = gi0 + (r0 - 32) + r;
                *(float2*)&wB[(b << 18) | (gi << 9) | gj] =
                    make_float2(prvR[r][0], prvR[r][1]);
            }
        }
        __syncthreads();

        n = n0 + s + 1;
        do_step(L1, L0, out, v2R, prvR, curR, base, c0,
                injCell, injV * srcT[n], m1Cell, m1Addr, m2Cell, m2Addr, n);
        if (s == K - 2 && wbThread) {     // curR holds f_{n0+K}
            int gj = gj0 + (c0 - 32);
#pragma unroll
            for (int r = 0; r < 8; ++r) {
                int gi = gi0 + (r0 - 32) + r;
                *(float2*)&wA[(b << 18) | (gi << 9) | gj] =
                    make_float2(curR[r][0], curR[r][1]);
            }
        }
        __syncthreads();
    }
}

// ---------------------------------------------------------------------------
extern "C" void kernel_launch(void* const* d_in, const int* in_sizes, int n_in,
                              void* d_out, int out_size, void* d_ws, size_t ws_size,
                              hipStream_t stream) {
    const float* x  = (const float*)d_in[0];
    const float* se = (const float*)d_in[1];
    float* out = (float*)d_out;

    float* ws = (float*)d_ws;
    const int FSZ = NB * NPTS;                 // 4 MB per field (floats)
    float* f[4] = {ws, ws + FSZ, ws + 2 * FSZ, ws + 3 * FSZ};
    int2*  dTT  = (int2*)(ws + 4 * FSZ);               // 64*1024 int2
    float* dSrc = (float*)(ws + 4 * FSZ + NTILES * NTHR * 2);

    static int   h_tt[NTILES * NTHR * 2];
    static float h_src[NT];
    static int   h_mx[NM], h_my[NM];
    for (int m = 0; m < NM; ++m) {
        double theta = (2.0 * M_PI * (double)m) / 256.0;
        h_mx[m] = (int)(256.0 + 200.0 * cos(theta));
        h_my[m] = (int)(256.0 + 200.0 * sin(theta));
    }
    for (int i = 0; i < NTILES * NTHR; ++i) { h_tt[2*i] = -1; h_tt[2*i+1] = 0; }
    for (int tile = 0; tile < NTILES; ++tile) {
        int bi0 = ((tile >> 3) << 6) - 32;
        int bj0 = ((tile & 7) << 6) - 32;
        for (int m = 0; m < NM; ++m) {
            int d = (h_mx[m] - bi0) & 511;
            int e = (h_my[m] - bj0) & 511;
            if (d >= WROWS || e >= WCOLS) continue;
            int tidx = (d >> 3) * 64 + (e >> 1);         // group*64 + colthread
            int cell = ((d & 7) << 1) | (e & 1);         // 0..15
            int basei = (tile * NTHR + tidx) * 2;
            if ((m & 3) == 0) h_tt[basei] = ((m >> 2) << 8) | cell;
            if (d >= 32 && d < 96 && e >= 32 && e < 96) {
                int half = 0x8000 | (cell << 8) | m;
                if (!(h_tt[basei + 1] & 0x8000)) h_tt[basei + 1] |= half;
                else                             h_tt[basei + 1] |= half << 16;
            }
        }
    }
    for (int t = 0; t < NT; ++t) {
        float tj  = (float)t * 2e-05f;
        float arg = (float)(2.0 * M_PI * 500.0) * tj;
        float d   = tj - 0.002f;
        float e   = -(d * d) / (float)(2.0 * 0.001 * 0.001);
        h_src[t]  = sinf(arg) * expf(e);
    }
    hipMemcpyAsync(dTT,  h_tt,  sizeof(h_tt),  hipMemcpyHostToDevice, stream);
    hipMemcpyAsync(dSrc, h_src, sizeof(h_src), hipMemcpyHostToDevice, stream);

    // zero chunk-0 input pair (f0A,f0B contiguous = 8 MB = 524288 float4)
    zero_kernel<<<2048, 256, 0, stream>>>((float4*)ws);

    for (int c = 0; c < NCH; ++c) {
        int p = c & 1, q = p ^ 1;
        chunk_kernel<<<NB * NTILES, NTHR, 0, stream>>>(
            x, se, out,
            f[2 * p], f[2 * p + 1],
            f[2 * q], f[2 * q + 1],
            dTT, dSrc, c * K);
    }
}

// Round 13
// 712.151 us; speedup vs baseline: 1.1305x; 1.1305x over previous
//
#include <hip/hip_runtime.h>
#include <math.h>

#define NXG 512
#define NPTS (NXG * NXG)
#define NB 4
#define NT 256
#define NM 256
#define K 16                // steps per chunk
#define NCH (NT / K)        // 16 chunks
#define WROWS 128           // window rows (64 interior + 2*32 halo)
#define WCOLS 128           // window cols
#define NTHR 512            // 16 row-groups x 32 cols; 8x4 cells per thread
#define NTILES 64           // 8x8 tiles (64x64 interior) cover 512x512
#define LROWS 72            // LDS slots: (16+2 pad) groups x 4 rows

// ---------------------------------------------------------------------------
__global__ __launch_bounds__(256) void zero_kernel(float4* __restrict__ p) {
    p[blockIdx.x * 256 + threadIdx.x] = make_float4(0.f, 0.f, 0.f, 0.f);
}

// DPP wave shifts (lane+-1). Cross-thread junk lands only in column-halo
// threads (col 0 / 31) — garbage-tolerant by the 32-wide halo argument.
__device__ __forceinline__ float dpp_left(float v) {
    return __int_as_float(__builtin_amdgcn_mov_dpp(__float_as_int(v),
                                                   0x138, 0xf, 0xf, true));
}
__device__ __forceinline__ float dpp_right(float v) {
    return __int_as_float(__builtin_amdgcn_mov_dpp(__float_as_int(v),
                                                   0x130, 0xf, 0xf, true));
}

// ---------------------------------------------------------------------------
// One row: reads cur rows + old dst[r] (the previous field), writes the new
// field IN PLACE into dst[r]. No temporaries survive the row — no spill.
// Hot path carries no injection/measurement code (patched post-step).
// ---------------------------------------------------------------------------
__device__ __forceinline__ void row_calc(
    const float (&cur)[8][4], float (&dst)[8][4],
    const float (&v2R)[8][4], int r,
    const float* __restrict__ xm2, const float* __restrict__ xm1,
    const float* __restrict__ xp1, const float* __restrict__ xp2)
{
    float y[8] = {dpp_left(cur[r][2]), dpp_left(cur[r][3]),
                  cur[r][0], cur[r][1], cur[r][2], cur[r][3],
                  dpp_right(cur[r][0]), dpp_right(cur[r][1])};
#pragma unroll
    for (int c = 0; c < 4; ++c) {
        float cc = cur[r][c];
        float sum1 = (xm1[c] + xp1[c]) + (y[c + 1] + y[c + 3]);
        float sum2 = (xm2[c] + xp2[c]) + (y[c] + y[c + 4]);
        float w = fmaf(-60.0f, cc, fmaf(16.0f, sum1, -sum2));
        dst[r][c] = fmaf(v2R[r][c], w, fmaf(2.0f, cc, -dst[r][c]));
    }
}

// ---------------------------------------------------------------------------
// One step: 8x4 cells in registers; x-halo rows -2,-1,+8,+9 from LDS;
// y-halo via DPP. Halo-free rows 2..5 first (overlap DS latency); new field
// written in place into nw (old prv); boundary rows 0,1,6,7 published to Ln.
// ---------------------------------------------------------------------------
__device__ __forceinline__ void do_step(
    const float* __restrict__ Lc, float* __restrict__ Ln,
    const float (&v2R)[8][4], float (&cur)[8][4], float (&nw)[8][4],
    int base, int c0)
{
    float4 a4 = *(const float4*)&Lc[(base - 2) * WCOLS + c0];  // row r0-2
    float4 b4 = *(const float4*)&Lc[(base - 1) * WCOLS + c0];  // row r0-1
    float4 c4 = *(const float4*)&Lc[(base + 4) * WCOLS + c0];  // row r0+8
    float4 d4 = *(const float4*)&Lc[(base + 5) * WCOLS + c0];  // row r0+9

#pragma unroll
    for (int r = 2; r < 6; ++r)
        row_calc(cur, nw, v2R, r, cur[r - 2], cur[r - 1], cur[r + 1], cur[r + 2]);

    float ha[4] = {a4.x, a4.y, a4.z, a4.w};
    float hb[4] = {b4.x, b4.y, b4.z, b4.w};
    row_calc(cur, nw, v2R, 0, ha, hb, cur[1], cur[2]);
    *(float4*)&Ln[(base + 0) * WCOLS + c0] =
        make_float4(nw[0][0], nw[0][1], nw[0][2], nw[0][3]);
    row_calc(cur, nw, v2R, 1, hb, cur[0], cur[2], cur[3]);
    *(float4*)&Ln[(base + 1) * WCOLS + c0] =
        make_float4(nw[1][0], nw[1][1], nw[1][2], nw[1][3]);

    float hc[4] = {c4.x, c4.y, c4.z, c4.w};
    float hd[4] = {d4.x, d4.y, d4.z, d4.w};
    row_calc(cur, nw, v2R, 6, cur[4], cur[5], cur[7], hc);
    *(float4*)&Ln[(base + 2) * WCOLS + c0] =
        make_float4(nw[6][0], nw[6][1], nw[6][2], nw[6][3]);
    row_calc(cur, nw, v2R, 7, cur[5], cur[6], hc, hd);
    *(float4*)&Ln[(base + 3) * WCOLS + c0] =
        make_float4(nw[7][0], nw[7][1], nw[7][2], nw[7][3]);
}

// ---------------------------------------------------------------------------
// Rare post-step patch: injection add (+ LDS boundary-row refresh) then
// measurement reads of the PATCHED new field. Only waves containing an
// inj/meas thread diverge into this.
// ---------------------------------------------------------------------------
__device__ __forceinline__ void patch_step(
    float (&f)[8][4], float* __restrict__ Ln, float* __restrict__ out,
    int base, int c0, int injCell, float addv,
    int m1Cell, int m1Addr, int m2Cell, int m2Addr, int n)
{
    if (injCell >= 0) {
#pragma unroll
        for (int r = 0; r < 8; ++r)
#pragma unroll
            for (int c = 0; c < 4; ++c)
                if (((r << 2) | c) == injCell) f[r][c] += addv;
        int ir = injCell >> 2;
        if (ir == 0) *(float4*)&Ln[(base + 0) * WCOLS + c0] = make_float4(f[0][0], f[0][1], f[0][2], f[0][3]);
        if (ir == 1) *(float4*)&Ln[(base + 1) * WCOLS + c0] = make_float4(f[1][0], f[1][1], f[1][2], f[1][3]);
        if (ir == 6) *(float4*)&Ln[(base + 2) * WCOLS + c0] = make_float4(f[6][0], f[6][1], f[6][2], f[6][3]);
        if (ir == 7) *(float4*)&Ln[(base + 3) * WCOLS + c0] = make_float4(f[7][0], f[7][1], f[7][2], f[7][3]);
    }
    if (m1Cell >= 0) {
        float v = 0.0f;
#pragma unroll
        for (int r = 0; r < 8; ++r)
#pragma unroll
            for (int c = 0; c < 4; ++c)
                if (((r << 2) | c) == m1Cell) v = f[r][c];
        out[m1Addr | n] = v;
    }
    if (m2Cell >= 0) {
        float v = 0.0f;
#pragma unroll
        for (int r = 0; r < 8; ++r)
#pragma unroll
            for (int c = 0; c < 4; ++c)
                if (((r << 2) | c) == m2Cell) v = f[r][c];
        out[m2Addr | n] = v;
    }
}

// ---------------------------------------------------------------------------
__global__ __launch_bounds__(NTHR, 2) void chunk_kernel(
    const float* __restrict__ x,       // (4,1,256,256)
    const float* __restrict__ se,      // (64,)
    float* __restrict__ out,           // (4,1,256,256) = [b][m][t]
    const float* __restrict__ gA,      // f_{n0}
    const float* __restrict__ gB,      // f_{n0-1}
    float* __restrict__ wA,            // f_{n0+K}
    float* __restrict__ wB,            // f_{n0+K-1}
    const int2* __restrict__ thrTab,   // NTILES x NTHR
    const float* __restrict__ srcT,
    int n0)
{
    __shared__ __align__(16) float L0[LROWS * WCOLS];
    __shared__ __align__(16) float L1[LROWS * WCOLS];

    const int tid = threadIdx.x;
    const int blk = blockIdx.x;
    const int b   = blk >> 6;          // batch
    const int tb  = blk & 63;          // tile
    const int gi0 = (tb >> 3) << 6;
    const int gj0 = (tb & 7) << 6;
    const int bi0 = gi0 - 32;
    const int bj0 = gj0 - 32;

    const int grp = tid >> 5;          // 0..15
    const int r0  = grp << 3;          // own window rows r0..r0+7
    const int c0  = (tid & 31) << 2;   // own window cols
    const int base = (grp + 1) << 2;   // LDS slot base

    // ---- prologue: own cells of f_{n0}, f_{n0-1}; v2/12 ----
    float curR[8][4], prvR[8][4], v2R[8][4];
    const float* gAb = gA + (b << 18);
    const float* gBb = gB + (b << 18);
#pragma unroll
    for (int r = 0; r < 8; ++r) {
        int gi = (bi0 + r0 + r) & 511;
        int gj = (bj0 + c0) & 511;
        float4 cv = *(const float4*)&gAb[(gi << 9) | gj];
        float4 pv = *(const float4*)&gBb[(gi << 9) | gj];
        curR[r][0] = cv.x; curR[r][1] = cv.y; curR[r][2] = cv.z; curR[r][3] = cv.w;
        prvR[r][0] = pv.x; prvR[r][1] = pv.y; prvR[r][2] = pv.z; prvR[r][3] = pv.w;
#pragma unroll
        for (int c = 0; c < 4; ++c) {
            int gjc = gj + c;
            float v;
            if (gi < 55 || gi >= 457 || gjc < 55 || gjc >= 457) v = 1e-6f;
            else if (gi >= 128 && gi < 384 && gjc >= 128 && gjc < 384)
                v = x[(b << 16) | ((gi - 128) << 8) | (gjc - 128)];
            else v = 1.5f;
            float a = (2e-05f * v) / 1e-04f;
            v2R[r][c] = a * a * (1.0f / 12.0f);
        }
    }

    // ---- inj/meas descriptor + wavelet preload ----
    const int2 tw = thrTab[(tb << 9) | tid];
    int injCell = -1;  float injV = 0.0f;
    if (tw.x >= 0) { injCell = tw.x & 31; injV = 0.09f * se[tw.x >> 8]; }
    int m1Cell = -1, m1Addr = 0, m2Cell = -1, m2Addr = 0;
    {
        int h1 = tw.y & 0xFFFF, h2 = (tw.y >> 16) & 0xFFFF;
        if (h1 & 0x8000) { m1Cell = (h1 >> 8) & 31; m1Addr = (b << 16) | ((h1 & 255) << 8); }
        if (h2 & 0x8000) { m2Cell = (h2 >> 8) & 31; m2Addr = (b << 16) | ((h2 & 255) << 8); }
    }
    const bool rare = (injCell >= 0) || (m1Cell >= 0) || (m2Cell >= 0);
    float sv[K];
#pragma unroll
    for (int k = 0; k < K; ++k) sv[k] = srcT[n0 + k];   // uniform

    // ---- publish f_{n0} boundary rows ----
    *(float4*)&L0[(base + 0) * WCOLS + c0] = make_float4(curR[0][0], curR[0][1], curR[0][2], curR[0][3]);
    *(float4*)&L0[(base + 1) * WCOLS + c0] = make_float4(curR[1][0], curR[1][1], curR[1][2], curR[1][3]);
    *(float4*)&L0[(base + 2) * WCOLS + c0] = make_float4(curR[6][0], curR[6][1], curR[6][2], curR[6][3]);
    *(float4*)&L0[(base + 3) * WCOLS + c0] = make_float4(curR[7][0], curR[7][1], curR[7][2], curR[7][3]);
    __syncthreads();

#pragma unroll
    for (int s = 0; s < K; s += 2) {
        do_step(L0, L1, v2R, curR, prvR, base, c0);    // prvR <- f_{n+1}
        if (rare) patch_step(prvR, L1, out, base, c0, injCell, injV * sv[s],
                             m1Cell, m1Addr, m2Cell, m2Addr, n0 + s);
        __syncthreads();

        do_step(L1, L0, v2R, prvR, curR, base, c0);    // curR <- f_{n+2}
        if (rare) patch_step(curR, L0, out, base, c0, injCell, injV * sv[s + 1],
                             m1Cell, m1Addr, m2Cell, m2Addr, n0 + s + 1);
        if (s + 2 < K) __syncthreads();
    }

    // ---- write back interior: curR = f_{n0+K}, prvR = f_{n0+K-1} ----
    if (r0 >= 32 && r0 < 96 && c0 >= 32 && c0 < 96) {
        int gj = gj0 + (c0 - 32);
#pragma unroll
        for (int r = 0; r < 8; ++r) {
            int gi = gi0 + (r0 - 32) + r;
            *(float4*)&wA[(b << 18) | (gi << 9) | gj] =
                make_float4(curR[r][0], curR[r][1], curR[r][2], curR[r][3]);
            *(float4*)&wB[(b << 18) | (gi << 9) | gj] =
                make_float4(prvR[r][0], prvR[r][1], prvR[r][2], prvR[r][3]);
        }
    }
}

// ---------------------------------------------------------------------------
extern "C" void kernel_launch(void* const* d_in, const int* in_sizes, int n_in,
                              void* d_out, int out_size, void* d_ws, size_t ws_size,
                              hipStream_t stream) {
    const float* x  = (const float*)d_in[0];
    const float* se = (const float*)d_in[1];
    float* out = (float*)d_out;

    float* ws = (float*)d_ws;
    const int FSZ = NB * NPTS;                 // 4 MB per field (floats)
    float* f[4] = {ws, ws + FSZ, ws + 2 * FSZ, ws + 3 * FSZ};
    int2*  dTT  = (int2*)(ws + 4 * FSZ);               // 64*512 int2
    float* dSrc = (float*)(ws + 4 * FSZ + NTILES * NTHR * 2);

    static int   h_tt[NTILES * NTHR * 2];
    static float h_src[NT];
    static int   h_mx[NM], h_my[NM];
    for (int m = 0; m < NM; ++m) {
        double theta = (2.0 * M_PI * (double)m) / 256.0;
        h_mx[m] = (int)(256.0 + 200.0 * cos(theta));
        h_my[m] = (int)(256.0 + 200.0 * sin(theta));
    }
    for (int i = 0; i < NTILES * NTHR; ++i) { h_tt[2*i] = -1; h_tt[2*i+1] = 0; }
    for (int tile = 0; tile < NTILES; ++tile) {
        int bi0 = ((tile >> 3) << 6) - 32;
        int bj0 = ((tile & 7) << 6) - 32;
        for (int m = 0; m < NM; ++m) {
            int d = (h_mx[m] - bi0) & 511;
            int e = (h_my[m] - bj0) & 511;
            if (d >= WROWS || e >= WCOLS) continue;
            int tidx = (d >> 3) * 32 + (e >> 2);
            int cell = ((d & 7) << 2) | (e & 3);         // 0..31
            int basei = (tile * NTHR + tidx) * 2;
            if ((m & 3) == 0) h_tt[basei] = ((m >> 2) << 8) | cell;
            if (d >= 32 && d < 96 && e >= 32 && e < 96) {
                int half = 0x8000 | (cell << 8) | m;
                if (!(h_tt[basei + 1] & 0x8000)) h_tt[basei + 1] |= half;
                else                             h_tt[basei + 1] |= half << 16;
            }
        }
    }
    for (int t = 0; t < NT; ++t) {
        float tj  = (float)t * 2e-05f;
        float arg = (float)(2.0 * M_PI * 500.0) * tj;
        float d   = tj - 0.002f;
        float e   = -(d * d) / (float)(2.0 * 0.001 * 0.001);
        h_src[t]  = sinf(arg) * expf(e);
    }
    hipMemcpyAsync(dTT,  h_tt,  sizeof(h_tt),  hipMemcpyHostToDevice, stream);
    hipMemcpyAsync(dSrc, h_src, sizeof(h_src), hipMemcpyHostToDevice, stream);

    // zero chunk-0 input pair (f0A,f0B contiguous = 8 MB = 524288 float4)
    zero_kernel<<<2048, 256, 0, stream>>>((float4*)ws);

    for (int c = 0; c < NCH; ++c) {
        int p = c & 1, q = p ^ 1;
        chunk_kernel<<<NB * NTILES, NTHR, 0, stream>>>(
            x, se, out,
            f[2 * p], f[2 * p + 1],
            f[2 * q], f[2 * q + 1],
            dTT, dSrc, c * K);
    }
}

// Round 14
// 678.892 us; speedup vs baseline: 1.1859x; 1.0490x over previous
//
#include <hip/hip_runtime.h>
#include <math.h>

#define NXG 512
#define NPTS (NXG * NXG)
#define NB 4
#define NT 256
#define NM 256
#define K 16                // steps per chunk
#define NCH (NT / K)        // 16 chunks
#define WROWS 128           // window rows (64 interior + 2*32 halo)
#define WCOLS 128           // window cols
#define NTHR 512            // 16 row-groups x 32 cols; 8x4 cells per thread
#define NTILES 64           // 8x8 tiles (64x64 interior) cover 512x512
#define LROWS 72            // LDS slots: (16+2 pad) groups x 4 rows

// ---------------------------------------------------------------------------
__global__ __launch_bounds__(256) void zero_kernel(float4* __restrict__ p) {
    p[blockIdx.x * 256 + threadIdx.x] = make_float4(0.f, 0.f, 0.f, 0.f);
}

// One-time: vel2/12 table in field layout (b,i,j) — removes the branchy
// per-chunk recomputation from the hot kernel.
__global__ __launch_bounds__(256) void vel2_kernel(const float* __restrict__ x,
                                                   float* __restrict__ vel2) {
    int gid = blockIdx.x * 256 + threadIdx.x;
    int b = gid >> 18;
    int idx = gid & (NPTS - 1);
    int i = idx >> 9, j = idx & 511;
    float v;
    if (i < 55 || i >= 457 || j < 55 || j >= 457) v = 1e-6f;
    else if (i >= 128 && i < 384 && j >= 128 && j < 384)
        v = x[(b << 16) | ((i - 128) << 8) | (j - 128)];
    else v = 1.5f;
    float a = (2e-05f * v) / 1e-04f;
    vel2[gid] = a * a * (1.0f / 12.0f);
}

// DPP wave shifts (lane+-1). Cross-thread junk lands only in column-halo
// threads (col 0 / 31) — garbage-tolerant by the 32-wide halo argument.
__device__ __forceinline__ float dpp_left(float v) {
    return __int_as_float(__builtin_amdgcn_mov_dpp(__float_as_int(v),
                                                   0x138, 0xf, 0xf, true));
}
__device__ __forceinline__ float dpp_right(float v) {
    return __int_as_float(__builtin_amdgcn_mov_dpp(__float_as_int(v),
                                                   0x130, 0xf, 0xf, true));
}

// ---------------------------------------------------------------------------
// One row: reads cur rows + old dst[r] (previous field), writes the new
// field IN PLACE into dst[r]. No inj/meas code in the hot path.
// ---------------------------------------------------------------------------
__device__ __forceinline__ void row_calc(
    const float (&cur)[8][4], float (&dst)[8][4],
    const float (&v2R)[8][4], int r,
    const float* __restrict__ xm2, const float* __restrict__ xm1,
    const float* __restrict__ xp1, const float* __restrict__ xp2)
{
    float y[8] = {dpp_left(cur[r][2]), dpp_left(cur[r][3]),
                  cur[r][0], cur[r][1], cur[r][2], cur[r][3],
                  dpp_right(cur[r][0]), dpp_right(cur[r][1])};
#pragma unroll
    for (int c = 0; c < 4; ++c) {
        float cc = cur[r][c];
        float sum1 = (xm1[c] + xp1[c]) + (y[c + 1] + y[c + 3]);
        float sum2 = (xm2[c] + xp2[c]) + (y[c] + y[c + 4]);
        float w = fmaf(-60.0f, cc, fmaf(16.0f, sum1, -sum2));
        dst[r][c] = fmaf(v2R[r][c], w, fmaf(2.0f, cc, -dst[r][c]));
    }
}

// ---------------------------------------------------------------------------
__device__ __forceinline__ void do_step(
    const float* __restrict__ Lc, float* __restrict__ Ln,
    const float (&v2R)[8][4], float (&cur)[8][4], float (&nw)[8][4],
    int base, int c0)
{
    float4 a4 = *(const float4*)&Lc[(base - 2) * WCOLS + c0];  // row r0-2
    float4 b4 = *(const float4*)&Lc[(base - 1) * WCOLS + c0];  // row r0-1
    float4 c4 = *(const float4*)&Lc[(base + 4) * WCOLS + c0];  // row r0+8
    float4 d4 = *(const float4*)&Lc[(base + 5) * WCOLS + c0];  // row r0+9

#pragma unroll
    for (int r = 2; r < 6; ++r)
        row_calc(cur, nw, v2R, r, cur[r - 2], cur[r - 1], cur[r + 1], cur[r + 2]);

    float ha[4] = {a4.x, a4.y, a4.z, a4.w};
    float hb[4] = {b4.x, b4.y, b4.z, b4.w};
    row_calc(cur, nw, v2R, 0, ha, hb, cur[1], cur[2]);
    *(float4*)&Ln[(base + 0) * WCOLS + c0] =
        make_float4(nw[0][0], nw[0][1], nw[0][2], nw[0][3]);
    row_calc(cur, nw, v2R, 1, hb, cur[0], cur[2], cur[3]);
    *(float4*)&Ln[(base + 1) * WCOLS + c0] =
        make_float4(nw[1][0], nw[1][1], nw[1][2], nw[1][3]);

    float hc[4] = {c4.x, c4.y, c4.z, c4.w};
    float hd[4] = {d4.x, d4.y, d4.z, d4.w};
    row_calc(cur, nw, v2R, 6, cur[4], cur[5], cur[7], hc);
    *(float4*)&Ln[(base + 2) * WCOLS + c0] =
        make_float4(nw[6][0], nw[6][1], nw[6][2], nw[6][3]);
    row_calc(cur, nw, v2R, 7, cur[5], cur[6], hc, hd);
    *(float4*)&Ln[(base + 3) * WCOLS + c0] =
        make_float4(nw[7][0], nw[7][1], nw[7][2], nw[7][3]);
}

// ---------------------------------------------------------------------------
// Rare post-step patch: injection add (+ LDS boundary refresh), then
// measurement reads of the PATCHED new field.
// ---------------------------------------------------------------------------
__device__ __forceinline__ void patch_step(
    float (&f)[8][4], float* __restrict__ Ln, float* __restrict__ out,
    int base, int c0, int injCell, float addv,
    int m1Cell, int m1Addr, int m2Cell, int m2Addr, int n)
{
    if (injCell >= 0) {
#pragma unroll
        for (int r = 0; r < 8; ++r)
#pragma unroll
            for (int c = 0; c < 4; ++c)
                if (((r << 2) | c) == injCell) f[r][c] += addv;
        int ir = injCell >> 2;
        if (ir == 0) *(float4*)&Ln[(base + 0) * WCOLS + c0] = make_float4(f[0][0], f[0][1], f[0][2], f[0][3]);
        if (ir == 1) *(float4*)&Ln[(base + 1) * WCOLS + c0] = make_float4(f[1][0], f[1][1], f[1][2], f[1][3]);
        if (ir == 6) *(float4*)&Ln[(base + 2) * WCOLS + c0] = make_float4(f[6][0], f[6][1], f[6][2], f[6][3]);
        if (ir == 7) *(float4*)&Ln[(base + 3) * WCOLS + c0] = make_float4(f[7][0], f[7][1], f[7][2], f[7][3]);
    }
    if (m1Cell >= 0) {
        float v = 0.0f;
#pragma unroll
        for (int r = 0; r < 8; ++r)
#pragma unroll
            for (int c = 0; c < 4; ++c)
                if (((r << 2) | c) == m1Cell) v = f[r][c];
        out[m1Addr | n] = v;
    }
    if (m2Cell >= 0) {
        float v = 0.0f;
#pragma unroll
        for (int r = 0; r < 8; ++r)
#pragma unroll
            for (int c = 0; c < 4; ++c)
                if (((r << 2) | c) == m2Cell) v = f[r][c];
        out[m2Addr | n] = v;
    }
}

// ---------------------------------------------------------------------------
__global__ __launch_bounds__(NTHR, 2) void chunk_kernel(
    const float* __restrict__ se,      // (64,)
    float* __restrict__ out,           // (4,1,256,256) = [b][m][t]
    const float* __restrict__ gA,      // f_{n0}
    const float* __restrict__ gB,      // f_{n0-1}
    float* __restrict__ wA,            // f_{n0+K}
    float* __restrict__ wB,            // f_{n0+K-1}
    const float* __restrict__ vel2,    // precomputed v2/12, field layout
    const int2* __restrict__ thrTab,   // NTILES x NTHR
    const float* __restrict__ srcT,
    int n0)
{
    __shared__ __align__(16) float L0[LROWS * WCOLS];
    __shared__ __align__(16) float L1[LROWS * WCOLS];

    const int tid = threadIdx.x;
    const int blk = blockIdx.x;
    const int b   = blk >> 6;          // batch
    const int tb  = blk & 63;          // tile
    const int gi0 = (tb >> 3) << 6;
    const int gj0 = (tb & 7) << 6;
    const int bi0 = gi0 - 32;
    const int bj0 = gj0 - 32;

    const int grp = tid >> 5;          // 0..15
    const int r0  = grp << 3;          // own window rows r0..r0+7
    const int c0  = (tid & 31) << 2;   // own window cols
    const int base = (grp + 1) << 2;   // LDS slot base

    // ---- prologue: own cells of f_{n0}, f_{n0-1}, vel2 — all b128 loads ----
    float curR[8][4], prvR[8][4], v2R[8][4];
    const float* gAb = gA + (b << 18);
    const float* gBb = gB + (b << 18);
    const float* gVb = vel2 + (b << 18);
#pragma unroll
    for (int r = 0; r < 8; ++r) {
        int gi = (bi0 + r0 + r) & 511;
        int gj = (bj0 + c0) & 511;
        float4 cv = *(const float4*)&gAb[(gi << 9) | gj];
        float4 pv = *(const float4*)&gBb[(gi << 9) | gj];
        float4 vv = *(const float4*)&gVb[(gi << 9) | gj];
        curR[r][0] = cv.x; curR[r][1] = cv.y; curR[r][2] = cv.z; curR[r][3] = cv.w;
        prvR[r][0] = pv.x; prvR[r][1] = pv.y; prvR[r][2] = pv.z; prvR[r][3] = pv.w;
        v2R[r][0] = vv.x; v2R[r][1] = vv.y; v2R[r][2] = vv.z; v2R[r][3] = vv.w;
    }

    // ---- inj/meas descriptor ----
    const int2 tw = thrTab[(tb << 9) | tid];
    int injCell = -1;  float injV = 0.0f;
    if (tw.x >= 0) { injCell = tw.x & 31; injV = 0.09f * se[tw.x >> 8]; }
    int m1Cell = -1, m1Addr = 0, m2Cell = -1, m2Addr = 0;
    {
        int h1 = tw.y & 0xFFFF, h2 = (tw.y >> 16) & 0xFFFF;
        if (h1 & 0x8000) { m1Cell = (h1 >> 8) & 31; m1Addr = (b << 16) | ((h1 & 255) << 8); }
        if (h2 & 0x8000) { m2Cell = (h2 >> 8) & 31; m2Addr = (b << 16) | ((h2 & 255) << 8); }
    }
    const bool rare = (injCell >= 0) || (m1Cell >= 0) || (m2Cell >= 0);

    // ---- publish f_{n0} boundary rows ----
    *(float4*)&L0[(base + 0) * WCOLS + c0] = make_float4(curR[0][0], curR[0][1], curR[0][2], curR[0][3]);
    *(float4*)&L0[(base + 1) * WCOLS + c0] = make_float4(curR[1][0], curR[1][1], curR[1][2], curR[1][3]);
    *(float4*)&L0[(base + 2) * WCOLS + c0] = make_float4(curR[6][0], curR[6][1], curR[6][2], curR[6][3]);
    *(float4*)&L0[(base + 3) * WCOLS + c0] = make_float4(curR[7][0], curR[7][1], curR[7][2], curR[7][3]);
    __syncthreads();

#pragma unroll 1
    for (int s = 0; s < K; s += 2) {    // 2 steps/iter — body fits I-cache
        float sva = srcT[n0 + s];
        float svb = srcT[n0 + s + 1];

        do_step(L0, L1, v2R, curR, prvR, base, c0);    // prvR <- f_{n+1}
        if (rare) patch_step(prvR, L1, out, base, c0, injCell, injV * sva,
                             m1Cell, m1Addr, m2Cell, m2Addr, n0 + s);
        __syncthreads();

        do_step(L1, L0, v2R, prvR, curR, base, c0);    // curR <- f_{n+2}
        if (rare) patch_step(curR, L0, out, base, c0, injCell, injV * svb,
                             m1Cell, m1Addr, m2Cell, m2Addr, n0 + s + 1);
        if (s + 2 < K) __syncthreads();
    }

    // ---- write back interior: curR = f_{n0+K}, prvR = f_{n0+K-1} ----
    if (r0 >= 32 && r0 < 96 && c0 >= 32 && c0 < 96) {
        int gj = gj0 + (c0 - 32);
#pragma unroll
        for (int r = 0; r < 8; ++r) {
            int gi = gi0 + (r0 - 32) + r;
            *(float4*)&wA[(b << 18) | (gi << 9) | gj] =
                make_float4(curR[r][0], curR[r][1], curR[r][2], curR[r][3]);
            *(float4*)&wB[(b << 18) | (gi << 9) | gj] =
                make_float4(prvR[r][0], prvR[r][1], prvR[r][2], prvR[r][3]);
        }
    }
}

// ---------------------------------------------------------------------------
extern "C" void kernel_launch(void* const* d_in, const int* in_sizes, int n_in,
                              void* d_out, int out_size, void* d_ws, size_t ws_size,
                              hipStream_t stream) {
    const float* x  = (const float*)d_in[0];
    const float* se = (const float*)d_in[1];
    float* out = (float*)d_out;

    float* ws = (float*)d_ws;
    const int FSZ = NB * NPTS;                 // 4 MB per field (floats)
    float* f[4]  = {ws, ws + FSZ, ws + 2 * FSZ, ws + 3 * FSZ};
    float* dVel  = ws + 4 * FSZ;                        // 4 MB
    int2*  dTT   = (int2*)(ws + 5 * FSZ);               // 64*512 int2
    float* dSrc  = (float*)(ws + 5 * FSZ + NTILES * NTHR * 2);

    static int   h_tt[NTILES * NTHR * 2];
    static float h_src[NT];
    static int   h_mx[NM], h_my[NM];
    for (int m = 0; m < NM; ++m) {
        double theta = (2.0 * M_PI * (double)m) / 256.0;
        h_mx[m] = (int)(256.0 + 200.0 * cos(theta));
        h_my[m] = (int)(256.0 + 200.0 * sin(theta));
    }
    for (int i = 0; i < NTILES * NTHR; ++i) { h_tt[2*i] = -1; h_tt[2*i+1] = 0; }
    for (int tile = 0; tile < NTILES; ++tile) {
        int bi0 = ((tile >> 3) << 6) - 32;
        int bj0 = ((tile & 7) << 6) - 32;
        for (int m = 0; m < NM; ++m) {
            int d = (h_mx[m] - bi0) & 511;
            int e = (h_my[m] - bj0) & 511;
            if (d >= WROWS || e >= WCOLS) continue;
            int tidx = (d >> 3) * 32 + (e >> 2);
            int cell = ((d & 7) << 2) | (e & 3);         // 0..31
            int basei = (tile * NTHR + tidx) * 2;
            if ((m & 3) == 0) h_tt[basei] = ((m >> 2) << 8) | cell;
            if (d >= 32 && d < 96 && e >= 32 && e < 96) {
                int half = 0x8000 | (cell << 8) | m;
                if (!(h_tt[basei + 1] & 0x8000)) h_tt[basei + 1] |= half;
                else                             h_tt[basei + 1] |= half << 16;
            }
        }
    }
    for (int t = 0; t < NT; ++t) {
        float tj  = (float)t * 2e-05f;
        float arg = (float)(2.0 * M_PI * 500.0) * tj;
        float d   = tj - 0.002f;
        float e   = -(d * d) / (float)(2.0 * 0.001 * 0.001);
        h_src[t]  = sinf(arg) * expf(e);
    }
    hipMemcpyAsync(dTT,  h_tt,  sizeof(h_tt),  hipMemcpyHostToDevice, stream);
    hipMemcpyAsync(dSrc, h_src, sizeof(h_src), hipMemcpyHostToDevice, stream);

    // zero chunk-0 input pair (f0A,f0B contiguous = 8 MB = 524288 float4)
    zero_kernel<<<2048, 256, 0, stream>>>((float4*)ws);
    // one-time vel2/12 table
    vel2_kernel<<<NB * NPTS / 256, 256, 0, stream>>>(x, dVel);

    for (int c = 0; c < NCH; ++c) {
        int p = c & 1, q = p ^ 1;
        chunk_kernel<<<NB * NTILES, NTHR, 0, stream>>>(
            se, out,
            f[2 * p], f[2 * p + 1],
            f[2 * q], f[2 * q + 1],
            dVel, dTT, dSrc, c * K);
    }
}